// Round 4
// baseline (212.357 us; speedup 1.0000x reference)
//
#include <hip/hip_runtime.h>
#include <stdint.h>

#define HH 512
#define WW 512
#define NIMG 64
#define OH 510
#define OW 510
#define NPB 4096                  // pair bins: 3 rows x 4 cols binary pattern = 12 bits
#define HBINS (NPB + 64)          // + 64 per-lane dummy bins
#define SEGR 32                   // output rows per big segment (34 loaded, 6.25% halo)
#define NSEG 16
#define NREP 4                    // global hist copies: 4 * 4096 * 4B = 64 KB ws (+ticket)
#define BLOCK 1024                // 16 waves/block
#define WPB (BLOCK / 64)
#define NBLK 256                  // 1 block/CU; 4096 waves total, 1 big task each
#define NWAVE (NBLK * WPB)
#define NBIG (NIMG * 2 * NSEG * 2)   // 4096 big wave-tasks
#define TICKET (NREP * NPB)          // ticket slot index in rep[]

typedef float f4 __attribute__((ext_vector_type(4)));

// Pinned load, flat VGPR-address form. volatile => program order kept among asm.
__device__ __forceinline__ f4 ldg4(const float* addr) {
    f4 r;
    asm volatile("global_load_dwordx4 %0, %1, off" : "=v"(r) : "v"(addr));
    return r;
}
// Wait until <=N of MY loads outstanding; "+v" tie orders consumption of x after it.
template<int N>
__device__ __forceinline__ void waitv(f4& x) {
    if      constexpr (N == 7) asm volatile("s_waitcnt vmcnt(7)" : "+v"(x));
    else if constexpr (N == 6) asm volatile("s_waitcnt vmcnt(6)" : "+v"(x));
    else if constexpr (N == 5) asm volatile("s_waitcnt vmcnt(5)" : "+v"(x));
    else if constexpr (N == 4) asm volatile("s_waitcnt vmcnt(4)" : "+v"(x));
    else if constexpr (N == 3) asm volatile("s_waitcnt vmcnt(3)" : "+v"(x));
    else if constexpr (N == 2) asm volatile("s_waitcnt vmcnt(2)" : "+v"(x));
    else if constexpr (N == 1) asm volatile("s_waitcnt vmcnt(1)" : "+v"(x));
    else                       asm volatile("s_waitcnt vmcnt(0)" : "+v"(x));
}

// Reference binarization ((x*0.5+0.5)*255 > 127.5) is exactly (x > 2^-24) in f32.
#define BINC 0x1p-24f

__device__ __forceinline__ int pack4(f4 v) {
    return (v.x > BINC) | ((v.y > BINC) << 1) | ((v.z > BINC) << 2) | ((v.w > BINC) << 3);
}

// Read wall is ~3.2 TB/s (fabric read direction; L3-warm == HBM-cold measured).
// Only lever: fewer bytes. SEGR=32 cuts halo overfetch 12.5% -> 6.25%.
// Reduce is fused into the last-finishing block (device-scope ticket) to drop
// the third launch + inter-launch gap from the fixed tail.
__global__ __launch_bounds__(BLOCK) void hist_kernel(const float* __restrict__ inp,
                                                     const float* __restrict__ tgt,
                                                     int* __restrict__ rep,
                                                     float* __restrict__ out) {
    __shared__ int hist[HBINS];
    __shared__ int sh[512];
    __shared__ double sd[512];
    __shared__ int lastflag;
    const int tid  = threadIdx.x;
    const int lane = tid & 63;
    const int wave = tid >> 6;

    for (int i = tid; i < HBINS; i += BLOCK) hist[i] = 0;
    __syncthreads();

    const int wid   = blockIdx.x * WPB + wave;
    const int dummy = NPB + ((lane + wave * 8) & 63);   // per-lane dummy bin
    const bool ln_ok = (lane < 63);                     // lane 63's (j=2,3) pair invalid

    {
        const int task = wid;                           // one big task per wave
        const int tile = task & 1;
        const int seg  = (task >> 1) & (NSEG - 1);
        const int t    = (task >> 5) & 1;
        const int img  = task >> 6;
        const int r0   = seg * SEGR;
        const int R    = min(SEGR, OH - r0);            // 32 (seg 15: 30)
        const int c0   = tile * 256 + 4 * lane;         // lane's first col (16B aligned)
        const int sign = 1 - 2 * t;
        const float* base = (t ? tgt : inp) + (size_t)img * (HH * WW) + c0;
        auto ap = [&](int rel) { return base + (size_t)min(r0 + rel, HH - 1) * WW; };

        // ring of 8, every load consumed by a matching wait (no dead dests)
        f4 X[8];
        #pragma unroll
        for (int q = 0; q < 8; ++q) X[q] = ldg4(ap(q));

        int n0, n1, n2;
        waitv<7>(X[0]);
        { int nib = pack4(X[0]); n0 = nib | (__shfl_down(nib, 1) << 4); }
        X[0] = ldg4(ap(8));
        waitv<7>(X[1]);
        { int nib = pack4(X[1]); n1 = nib | (__shfl_down(nib, 1) << 4); }
        X[1] = ldg4(ap(9));

        // issued rows 0..9; refills rows 10..33 at o=0..23; drain o=25..31
        #define STEP(o, W) { \
            f4& Xs = X[((o) + 2) & 7]; \
            waitv<W>(Xs); \
            int nib = pack4(Xs); \
            n2 = nib | (__shfl_down(nib, 1) << 4); \
            if ((o) <= 23) Xs = ldg4(ap((o) + 10)); \
            if ((o) < R) { \
                int p01 = (n0 & 15) | ((n1 & 15) << 4) | ((n2 & 15) << 8); \
                int p23 = ((n0 >> 2) & 15) | (((n1 >> 2) & 15) << 4) \
                        | (((n2 >> 2) & 15) << 8); \
                atomicAdd(&hist[p01], sign); \
                atomicAdd(&hist[ln_ok ? p23 : dummy], sign); \
            } \
            n0 = n1; n1 = n2; }

        STEP(0, 7)  STEP(1, 7)  STEP(2, 7)  STEP(3, 7)
        STEP(4, 7)  STEP(5, 7)  STEP(6, 7)  STEP(7, 7)
        STEP(8, 7)  STEP(9, 7)  STEP(10, 7) STEP(11, 7)
        STEP(12, 7) STEP(13, 7) STEP(14, 7) STEP(15, 7)
        STEP(16, 7) STEP(17, 7) STEP(18, 7) STEP(19, 7)
        STEP(20, 7) STEP(21, 7) STEP(22, 7) STEP(23, 7)
        STEP(24, 7) STEP(25, 6) STEP(26, 5) STEP(27, 4)
        STEP(28, 3) STEP(29, 2) STEP(30, 1) STEP(31, 0)
        #undef STEP
        // vmcnt == 0 here: all loads consumed.
    }

    if ((wid & 3) == 0) {
        // ---- seam task: output cols 254,255 (inputs 254..257) pair to one bin ----
        const int idx = wid >> 2;                       // 0..1023, spread across blocks
        const int seg = idx & 7;
        const int t   = (idx >> 3) & 1;
        const int img = idx >> 4;
        const int sign = 1 - 2 * t;
        const int r   = seg * 64 + lane;
        const bool v  = (r < OH);
        const float* bp = (t ? tgt : inp) + (size_t)img * (HH * WW);
        int p[3];
        #pragma unroll
        for (int q = 0; q < 3; ++q) {
            const float* rowp = bp + (size_t)min(r + q, HH - 1) * WW;
            float2 A = *(const float2*)(rowp + 254);    // cols 254,255 (8B aligned)
            float2 B = *(const float2*)(rowp + 256);    // cols 256,257
            p[q] = (A.x > BINC) | ((A.y > BINC) << 1)
                 | ((B.x > BINC) << 2) | ((B.y > BINC) << 3);
        }
        int pair = p[0] | (p[1] << 4) | (p[2] << 8);
        atomicAdd(&hist[v ? pair : dummy], sign);
    }

    __syncthreads();
    const int rid = blockIdx.x & (NREP - 1);
    for (int i = tid; i < NPB; i += BLOCK) {            // flush real pair-bins only
        int vv = hist[i];
        if (vv) atomicAdd(&rep[rid * NPB + i], vv);
    }

    // ---- fused reduction: last block to arrive expands pairs -> codes ----
    __threadfence();
    if (tid == 0) {
        int prev = __hip_atomic_fetch_add(&rep[TICKET], 1, __ATOMIC_ACQ_REL,
                                          __HIP_MEMORY_SCOPE_AGENT);
        lastflag = (prev == NBLK - 1);
    }
    __syncthreads();
    if (!lastflag) return;

    if (tid < 512) sh[tid] = 0;
    __syncthreads();
    // pair p: row nibbles a=p[0:4), b=p[4:8), c=p[8:12); left code uses bits 0..2
    // of each nibble, right code uses bits 1..3 (fixed bijection of labelings).
    #pragma unroll
    for (int k = 0; k < NPB / BLOCK; ++k) {
        int p = tid + k * BLOCK;
        int s = 0;
        #pragma unroll
        for (int r = 0; r < NREP; ++r)       // agent-scope loads: see other XCDs' flushes
            s += __hip_atomic_load(&rep[r * NPB + p], __ATOMIC_RELAXED,
                                   __HIP_MEMORY_SCOPE_AGENT);
        if (s) {
            int f0 = (p & 7) | (((p >> 4) & 7) << 3) | (((p >> 8) & 7) << 6);
            int f1 = ((p >> 1) & 7) | (((p >> 5) & 7) << 3) | (((p >> 9) & 7) << 6);
            atomicAdd(&sh[f0], s);
            atomicAdd(&sh[f1], s);
        }
    }
    __syncthreads();

    if (tid < 512) { double d = (double)sh[tid]; sd[tid] = d * d; }
    __syncthreads();
    for (int stp = 256; stp > 0; stp >>= 1) {
        if (tid < stp) sd[tid] += sd[tid + stp];
        __syncthreads();
    }
    if (tid == 0) {
        const double n = (double)NIMG * OH * OW;   // 16,646,400
        out[0] = (float)(sd[0] / (n * n) / 512.0 / 64.0);
    }
}

extern "C" void kernel_launch(void* const* d_in, const int* in_sizes, int n_in,
                              void* d_out, int out_size, void* d_ws, size_t ws_size,
                              hipStream_t stream) {
    const float* inp = (const float*)d_in[0];
    const float* tgt = (const float*)d_in[1];
    float* out = (float*)d_out;
    int* rep = (int*)d_ws;                      // NREP*NPB ints + ticket = 64 KB + 4

    hipMemsetAsync(rep, 0, (NREP * NPB + 1) * sizeof(int), stream);
    hist_kernel<<<NBLK, BLOCK, 0, stream>>>(inp, tgt, rep, out);
}

// Round 5
// 151.768 us; speedup vs baseline: 1.3992x; 1.3992x over previous
//
#include <hip/hip_runtime.h>
#include <stdint.h>

#define HH 512
#define WW 512
#define NIMG 64
#define OH 510
#define OW 510
#define NPB 4096                  // pair bins: 3 rows x 4 cols binary pattern = 12 bits
#define HBINS (NPB + 64)          // + 64 per-lane dummy bins
#define SEGR 32                   // output rows per big segment (34 loaded, 6.25% halo)
#define NSEG 16
#define NREP 8                    // global hist copies: 8 * 4096 * 4B = 128 KB ws
#define BLOCK 512                 // 8 waves/block; 512 blocks = 2 blocks/CU (slack!)
#define WPB (BLOCK / 64)
#define NBLK 512
#define NWAVE (NBLK * WPB)        // 4096 waves; each does exactly 1 big task
#define NBIG (NIMG * 2 * NSEG * 2)   // 4096 big wave-tasks
#define NSEAM (NIMG * 2 * 8)         // 1024 seam wave-tasks (1/4 of waves)

typedef float f4 __attribute__((ext_vector_type(4)));

// Pinned non-temporal load. R0-R3 showed a ~3.2 TB/s read wall independent of
// L3 vs HBM residency => CU-side (L1 alloc/miss path). nt = streaming policy.
__device__ __forceinline__ f4 ldg4(const float* addr) {
    f4 r;
    asm volatile("global_load_dwordx4 %0, %1, off nt" : "=v"(r) : "v"(addr));
    return r;
}
// Wait until <=N of MY loads outstanding; "+v" tie orders consumption of x after it.
template<int N>
__device__ __forceinline__ void waitv(f4& x) {
    if      constexpr (N == 7) asm volatile("s_waitcnt vmcnt(7)" : "+v"(x));
    else if constexpr (N == 6) asm volatile("s_waitcnt vmcnt(6)" : "+v"(x));
    else if constexpr (N == 5) asm volatile("s_waitcnt vmcnt(5)" : "+v"(x));
    else if constexpr (N == 4) asm volatile("s_waitcnt vmcnt(4)" : "+v"(x));
    else if constexpr (N == 3) asm volatile("s_waitcnt vmcnt(3)" : "+v"(x));
    else if constexpr (N == 2) asm volatile("s_waitcnt vmcnt(2)" : "+v"(x));
    else if constexpr (N == 1) asm volatile("s_waitcnt vmcnt(1)" : "+v"(x));
    else                       asm volatile("s_waitcnt vmcnt(0)" : "+v"(x));
}

// Reference binarization ((x*0.5+0.5)*255 > 127.5) is exactly (x > 2^-24) in f32.
#define BINC 0x1p-24f

__device__ __forceinline__ int pack4(f4 v) {
    return (v.x > BINC) | ((v.y > BINC) << 1) | ((v.z > BINC) << 2) | ((v.w > BINC) << 3);
}

// Pair-histogram: adjacent output codes share 6/9 pixels -> 12-bit pair-bin,
// one ds_add per TWO codes. Grid: 512 blocks x 8 waves (2 blocks/CU resident --
// R4 proved 1-block-per-CU grids are fragile: 2.5x regression from dispatch
// imbalance). SEGR=32 cuts halo overfetch 12.5% -> 6.25%.
__global__ __launch_bounds__(BLOCK) void hist_kernel(const float* __restrict__ inp,
                                                     const float* __restrict__ tgt,
                                                     int* __restrict__ rep) {
    __shared__ int hist[HBINS];
    const int tid  = threadIdx.x;
    const int lane = tid & 63;
    const int wave = tid >> 6;

    for (int i = tid; i < HBINS; i += BLOCK) hist[i] = 0;
    __syncthreads();

    const int wid   = blockIdx.x * WPB + wave;
    const int dummy = NPB + ((lane + wave * 8) & 63);   // per-lane dummy bin
    const bool ln_ok = (lane < 63);                     // lane 63's (j=2,3) pair invalid

    {
        const int task = wid;                           // one big task per wave
        const int tile = task & 1;
        const int seg  = (task >> 1) & (NSEG - 1);
        const int t    = (task >> 5) & 1;
        const int img  = task >> 6;
        const int r0   = seg * SEGR;
        const int R    = min(SEGR, OH - r0);            // 32 (seg 15: 30)
        const int c0   = tile * 256 + 4 * lane;         // lane's first col (16B aligned)
        const int sign = 1 - 2 * t;
        const float* base = (t ? tgt : inp) + (size_t)img * (HH * WW) + c0;
        auto ap = [&](int rel) { return base + (size_t)min(r0 + rel, HH - 1) * WW; };

        // ring of 8, every load consumed by a matching wait (no dead dests)
        f4 X[8];
        #pragma unroll
        for (int q = 0; q < 8; ++q) X[q] = ldg4(ap(q));

        int n0, n1, n2;
        waitv<7>(X[0]);
        { int nib = pack4(X[0]); n0 = nib | (__shfl_down(nib, 1) << 4); }
        X[0] = ldg4(ap(8));
        waitv<7>(X[1]);
        { int nib = pack4(X[1]); n1 = nib | (__shfl_down(nib, 1) << 4); }
        X[1] = ldg4(ap(9));

        // issued rows 0..9; refills rows 10..33 at o=0..23; drain o=25..31
        #define STEP(o, W) { \
            f4& Xs = X[((o) + 2) & 7]; \
            waitv<W>(Xs); \
            int nib = pack4(Xs); \
            n2 = nib | (__shfl_down(nib, 1) << 4); \
            if ((o) <= 23) Xs = ldg4(ap((o) + 10)); \
            if ((o) < R) { \
                int p01 = (n0 & 15) | ((n1 & 15) << 4) | ((n2 & 15) << 8); \
                int p23 = ((n0 >> 2) & 15) | (((n1 >> 2) & 15) << 4) \
                        | (((n2 >> 2) & 15) << 8); \
                atomicAdd(&hist[p01], sign); \
                atomicAdd(&hist[ln_ok ? p23 : dummy], sign); \
            } \
            n0 = n1; n1 = n2; }

        STEP(0, 7)  STEP(1, 7)  STEP(2, 7)  STEP(3, 7)
        STEP(4, 7)  STEP(5, 7)  STEP(6, 7)  STEP(7, 7)
        STEP(8, 7)  STEP(9, 7)  STEP(10, 7) STEP(11, 7)
        STEP(12, 7) STEP(13, 7) STEP(14, 7) STEP(15, 7)
        STEP(16, 7) STEP(17, 7) STEP(18, 7) STEP(19, 7)
        STEP(20, 7) STEP(21, 7) STEP(22, 7) STEP(23, 7)
        STEP(24, 7) STEP(25, 6) STEP(26, 5) STEP(27, 4)
        STEP(28, 3) STEP(29, 2) STEP(30, 1) STEP(31, 0)
        #undef STEP
        // vmcnt == 0 here: all loads consumed.
    }

    if ((wid & 3) == 0) {
        // ---- seam task: output cols 254,255 (inputs 254..257) pair to one bin ----
        const int idx = wid >> 2;                       // 0..1023, spread across blocks
        const int seg = idx & 7;
        const int t   = (idx >> 3) & 1;
        const int img = idx >> 4;
        const int sign = 1 - 2 * t;
        const int r   = seg * 64 + lane;
        const bool v  = (r < OH);
        const float* bp = (t ? tgt : inp) + (size_t)img * (HH * WW);
        int p[3];
        #pragma unroll
        for (int q = 0; q < 3; ++q) {
            const float* rowp = bp + (size_t)min(r + q, HH - 1) * WW;
            float2 A = *(const float2*)(rowp + 254);    // cols 254,255 (8B aligned)
            float2 B = *(const float2*)(rowp + 256);    // cols 256,257
            p[q] = (A.x > BINC) | ((A.y > BINC) << 1)
                 | ((B.x > BINC) << 2) | ((B.y > BINC) << 3);
        }
        int pair = p[0] | (p[1] << 4) | (p[2] << 8);
        atomicAdd(&hist[v ? pair : dummy], sign);
    }

    __syncthreads();
    const int rid = blockIdx.x & (NREP - 1);
    for (int i = tid; i < NPB; i += BLOCK) {            // flush real pair-bins only
        int vv = hist[i];
        if (vv) atomicAdd(&rep[rid * NPB + i], vv);
    }
}

__global__ __launch_bounds__(1024) void reduce_kernel(const int* __restrict__ rep,
                                                      float* __restrict__ out) {
    __shared__ int sh[512];          // signed single-code diff counts
    __shared__ double sd[512];
    const int tid = threadIdx.x;
    if (tid < 512) sh[tid] = 0;
    __syncthreads();

    // Expand pair-bins -> the two constituent 9-bit codes.
    // pair p: row nibbles a=p[0:4), b=p[4:8), c=p[8:12); left code uses bits 0..2
    // of each nibble, right code uses bits 1..3 (fixed bijection of labelings).
    #pragma unroll
    for (int k = 0; k < NPB / 1024; ++k) {
        int p = tid + k * 1024;
        int s = 0;
        #pragma unroll
        for (int r = 0; r < NREP; ++r) s += rep[r * NPB + p];   // coalesced
        if (s) {
            int f0 = (p & 7) | (((p >> 4) & 7) << 3) | (((p >> 8) & 7) << 6);
            int f1 = ((p >> 1) & 7) | (((p >> 5) & 7) << 3) | (((p >> 9) & 7) << 6);
            atomicAdd(&sh[f0], s);
            atomicAdd(&sh[f1], s);
        }
    }
    __syncthreads();

    if (tid < 512) { double d = (double)sh[tid]; sd[tid] = d * d; }
    __syncthreads();
    for (int stp = 256; stp > 0; stp >>= 1) {
        if (tid < stp) sd[tid] += sd[tid + stp];
        __syncthreads();
    }
    if (tid == 0) {
        const double n = (double)NIMG * OH * OW;   // 16,646,400
        out[0] = (float)(sd[0] / (n * n) / 512.0 / 64.0);
    }
}

extern "C" void kernel_launch(void* const* d_in, const int* in_sizes, int n_in,
                              void* d_out, int out_size, void* d_ws, size_t ws_size,
                              hipStream_t stream) {
    const float* inp = (const float*)d_in[0];
    const float* tgt = (const float*)d_in[1];
    float* out = (float*)d_out;
    int* rep = (int*)d_ws;                      // NREP*NPB ints = 128 KB in workspace

    hipMemsetAsync(rep, 0, NREP * NPB * sizeof(int), stream);
    hist_kernel<<<NBLK, BLOCK, 0, stream>>>(inp, tgt, rep);
    reduce_kernel<<<1, 1024, 0, stream>>>(rep, out);
}